// Round 7
// baseline (160.733 us; speedup 1.0000x reference)
//
#include <hip/hip_runtime.h>
#include <hip/hip_bf16.h>
#include <math.h>

#define BB 32
#define NN 512

typedef _Float16 f16x8 __attribute__((ext_vector_type(8)));
typedef __fp16  fp16x2 __attribute__((ext_vector_type(2)));
typedef float f32x4 __attribute__((ext_vector_type(4)));

#define MFMA16(a, b, c) __builtin_amdgcn_mfma_f32_16x16x32_f16(a, b, c, 0, 0, 0)

union AF { f16x8 v; unsigned int u[4]; };

// async global->LDS; LDS dest = wave-uniform base + lane*size
__device__ __forceinline__ void gload_lds16(const void* g, void* l) {
    __builtin_amdgcn_global_load_lds(
        (const __attribute__((address_space(1))) unsigned int*)g,
        (__attribute__((address_space(3))) unsigned int*)l, 16, 0, 0);
}
__device__ __forceinline__ void gload_lds4(const void* g, void* l) {
    __builtin_amdgcn_global_load_lds(
        (const __attribute__((address_space(1))) unsigned int*)g,
        (__attribute__((address_space(3))) unsigned int*)l, 4, 0, 0);
}

// monotonic uint key for fp32 atomicMax (exact max, order-independent)
__device__ __forceinline__ unsigned fenc(float f) {
    unsigned b = __float_as_uint(f);
    return (b & 0x80000000u) ? ~b : (b | 0x80000000u);
}
__device__ __forceinline__ float fdec(unsigned u) {
    return __uint_as_float((u & 0x80000000u) ? (u ^ 0x80000000u) : ~u);
}

// ============ W^T fp16 prep (W0 + W1 fused) + maxd key zero-init ===========
__global__ __launch_bounds__(256) void k_wt_prep(
    const float* __restrict__ W0, _Float16* __restrict__ W0T,
    const float* __restrict__ W1, _Float16* __restrict__ W1T,
    unsigned* __restrict__ maxdz)
{
    int id = blockIdx.x * 256 + threadIdx.x;   // 0..4607
    if (id < 512) maxdz[id] = 0u;              // maxd0+maxd1 keys (= -inf)
    const float* W; _Float16* WT; int KT, task;
    if (id < 512) { W = W0; WT = W0T; KT = 64;  task = id; }
    else          { W = W1; WT = W1T; KT = 512; task = id - 512; }
    int n = task & 63, gabs = task >> 6;
    int c = gabs >> 3, g = gabs & 7;
    f16x8 hv;
#pragma unroll
    for (int e = 0; e < 8; ++e)
        hv[e] = (_Float16)W[(size_t)(gabs * 8 + e) * 64 + n];
    *(f16x8*)(WT + (size_t)n * KT + c * 64 + (g ^ (n & 7)) * 8) = hv;
}

// ============ 16-row epilogue (gemm0, 256 threads) =========================
static __device__ __forceinline__ void epi16(
    const float* ctile, const float* asd_f, int row0, int t,
    float* __restrict__ s, float* __restrict__ dTg, _Float16* __restrict__ hpT,
    float* dmax_lds, unsigned* __restrict__ maxd_out)
{
    int b = row0 >> 9, jb = row0 & 511;
    if (t < 128) {
        int rr = t >> 3, h = t & 7;
        float sv = 0.f, dv = 0.f;
#pragma unroll
        for (int f = 0; f < 64; ++f) {
            float hv = ctile[rr * 66 + f];
            sv = fmaf(hv, asd_f[f * 8 + h], sv);
            dv = fmaf(hv, asd_f[512 + f * 8 + h], dv);
        }
        s[((size_t)b * NN + jb + rr) * 8 + h] = sv;
        dTg[((size_t)b * 8 + h) * NN + jb + rr] = dv;
        dmax_lds[t] = dv;
    } else if (t < 256) {
        int t2 = t - 128;
        int f = t2 >> 1, jl = (t2 & 1) * 8;
        f16x8 hv;
#pragma unroll
        for (int e = 0; e < 8; ++e)
            hv[e] = (_Float16)ctile[(jl + e) * 66 + f];
        *(f16x8*)(hpT + ((size_t)b * 64 + f) * NN + jb + jl) = hv;
    }
    __syncthreads();
    if (t < 8) {
        float m = dmax_lds[t];
#pragma unroll
        for (int k = 1; k < 16; ++k) m = fmaxf(m, dmax_lds[t + 8 * k]);
        atomicMax(maxd_out + (b * 8 + t), fenc(m));
    }
}

// ============ 32-row epilogue (attn, 512 threads) ==========================
static __device__ __forceinline__ void epi32(
    const float* ctile, const float* asd_f, int row0, int t,
    float* __restrict__ s, float* __restrict__ dTg, _Float16* __restrict__ hpT,
    float* dmax_lds, unsigned* __restrict__ maxd_out)
{
    int b = row0 >> 9, jb = row0 & 511;
    if (t < 256) {
        int rr = t >> 3, h = t & 7;
        float sv = 0.f, dv = 0.f;
#pragma unroll
        for (int f = 0; f < 64; ++f) {
            float hv = ctile[rr * 66 + f];
            sv = fmaf(hv, asd_f[f * 8 + h], sv);
            dv = fmaf(hv, asd_f[512 + f * 8 + h], dv);
        }
        s[((size_t)b * NN + jb + rr) * 8 + h] = sv;
        dTg[((size_t)b * 8 + h) * NN + jb + rr] = dv;
        dmax_lds[t] = dv;
    } else {
        int t2 = t - 256;
        int f = t2 >> 2, jl = (t2 & 3) * 8;
        f16x8 hv;
#pragma unroll
        for (int e = 0; e < 8; ++e)
            hv[e] = (_Float16)ctile[(jl + e) * 66 + f];
        *(f16x8*)(hpT + ((size_t)b * 64 + f) * NN + jb + jl) = hv;
    }
    __syncthreads();
    if (t < 8) {
        float m = dmax_lds[t];
#pragma unroll
        for (int k = 1; k < 32; ++k) m = fmaxf(m, dmax_lds[t + 8 * k]);
        atomicMax(maxd_out + (b * 8 + t), fenc(m));
    }
}

// ============ Layer-0 GEMM + adj bit-mask prep ==============================
__global__ __launch_bounds__(256) void k_gemm0(
    const float* __restrict__ x, const _Float16* __restrict__ W0T,
    const float* __restrict__ a_src, const float* __restrict__ a_dst,
    const float* __restrict__ adj, unsigned long long* __restrict__ adjb,
    float* __restrict__ s, float* __restrict__ dTg, _Float16* __restrict__ hpT,
    unsigned* __restrict__ maxd)
{
    __shared__ float ctile[16 * 66];
    __shared__ float asd_f[1024];
    __shared__ unsigned int mrow[16][16];
    __shared__ float dmax[128];
    int t = threadIdx.x, row0 = blockIdx.x * 16;
    int lane = t & 63, w = t >> 6, cn = lane & 15, rq = lane >> 4;

    // ---- issue adj loads early: thread t covers row (t>>4), j in [seg*32,+32)
    int ar = t >> 4, seg = t & 15;
    const float* ap = adj + (size_t)(row0 + ar) * NN + seg * 32;
    float4 av[8];
#pragma unroll
    for (int q = 0; q < 8; ++q) av[q] = ((const float4*)ap)[q];

    ((float4*)asd_f)[t] = (t < 128) ? ((const float4*)a_src)[t]
                                    : ((const float4*)a_dst)[t - 128];
    f32x4 acc;
#pragma unroll
    for (int e = 0; e < 4; ++e) acc[e] = 0.f;
#pragma unroll
    for (int ks = 0; ks < 2; ++ks) {
        const float* xp = x + (size_t)(row0 + cn) * 64 + ks * 32 + rq * 8;
        float4 x0 = *(const float4*)xp, x1 = *(const float4*)(xp + 4);
        f16x8 ah = {(_Float16)x0.x, (_Float16)x0.y, (_Float16)x0.z, (_Float16)x0.w,
                    (_Float16)x1.x, (_Float16)x1.y, (_Float16)x1.z, (_Float16)x1.w};
        int nn = w * 16 + cn;
        f16x8 bh = *(const f16x8*)(W0T + (size_t)nn * 64 + (((ks * 4 + rq) ^ (nn & 7)) * 8));
        acc = MFMA16(ah, bh, acc);
    }
#pragma unroll
    for (int r = 0; r < 4; ++r)
        ctile[(rq * 4 + r) * 66 + w * 16 + cn] = acc[r];
    __syncthreads();
    epi16(ctile, asd_f, row0, t, s, dTg, hpT, dmax, maxd);

    // ---- pack 32 adj entries -> u32 bits, fold self-loop, assemble u64s
    unsigned int m32 = 0;
#pragma unroll
    for (int q = 0; q < 8; ++q) {
        if (av[q].x != 0.f) m32 |= 1u << (q * 4 + 0);
        if (av[q].y != 0.f) m32 |= 1u << (q * 4 + 1);
        if (av[q].z != 0.f) m32 |= 1u << (q * 4 + 2);
        if (av[q].w != 0.f) m32 |= 1u << (q * 4 + 3);
    }
    int i = (row0 + ar) & (NN - 1);
    if ((i >> 5) == seg) m32 |= 1u << (i & 31);
    mrow[ar][seg] = m32;
    __syncthreads();
    if (t < 128) {
        int r = t >> 3, k = t & 7;
        unsigned long long u = (unsigned long long)mrow[r][2 * k]
                             | ((unsigned long long)mrow[r][2 * k + 1] << 32);
        adjb[(size_t)(row0 + r) * 8 + k] = u;
    }
}

// ============ fused attention v10: 32 ROWS x 8 heads per block ==============
// Grid 512, 8 waves x 512 thr; wave w = head w over TWO 16-row tiles.
// Per ks-step: 4 hT b128 reads serve 10 MFMAs (2 tiles x (4 PV + 1 RS));
// dd shared across tiles. hT/dd LDS traffic + barriers + epilogues HALVE vs
// v9b (LDS redundancy was the r6-falsified occupancy theory's real culprit).
// VGPR ~110 -> launch_bounds(512,4); 2 blocks/CU, 38.4KB smem.
#define PBUILD(AOUT, SV, M_, MBYTE, DDv)                                \
    do {                                                                \
        _Pragma("unroll")                                               \
        for (int e = 0; e < 8; e += 2) {                                \
            float pA[2];                                                \
            _Pragma("unroll")                                           \
            for (int q = 0; q < 2; ++q) {                               \
                int ee = e + q;                                         \
                bool con = (MBYTE >> ee) & 1u;                          \
                float e0 = SV + DDv[ee];                                \
                float l0 = fmaxf(e0, 0.2f * e0);                        \
                float p0 = __expf(l0 - M_);                             \
                pA[q] = (con && l0 != 0.f) ? p0 : 0.f;                  \
            }                                                           \
            fp16x2 ka = __builtin_amdgcn_cvt_pkrtz(pA[0], pA[1]);       \
            AOUT.u[e >> 1] = __builtin_bit_cast(unsigned int, ka);      \
        }                                                               \
    } while (0)

template<int MODE>
__global__ __launch_bounds__(512, 4) void k_attn_fused(
    const unsigned long long* __restrict__ adjb, const float* __restrict__ s,
    const float* __restrict__ dTg, const unsigned* __restrict__ maxd,
    const _Float16* __restrict__ hpT,
    const _Float16* __restrict__ W1T,
    const float* __restrict__ a_src, const float* __restrict__ a_dst,
    float* __restrict__ s_out, float* __restrict__ dTg_out,
    _Float16* __restrict__ hpT_out, unsigned* __restrict__ maxd_out,
    float* __restrict__ o_f)
{
    __shared__ __align__(16) char smem[38400];
    char* bufP = smem;                         // 8KB hT + 2KB dd
    char* bufQ = smem + 10240;

    int blk = blockIdx.x;                      // 0..511
    int vb = ((blk & 7) << 6) | (blk >> 3);    // XCD swizzle (512 = 8*64)
    int b = vb >> 4, i0 = (vb & 15) << 5;      // 32-row tile
    int row0 = vb * 32;                        // = b*512 + i0
    int t = threadIdx.x, lane = t & 63, w = t >> 6;   // w = head (0..7)
    int cn = lane & 15, rq = lane >> 4;
    int myrow = i0 + cn;                       // tile A row; tile B = +16

    const _Float16* hb = hpT + (size_t)b * 64 * NN;
    // hT staging: 512 threads cover all 64 rows; wave w rows 8w..8w+7,
    // base (w<<9) fp16 (1024B/wave). Source pre-swizzled granule.
    int f0 = t >> 3, g0 = t & 7;
    const _Float16* hsrc = hb + (size_t)f0 * NN + ((g0 ^ (f0 & 7)) * 8);
    // dd staging: wave w stages head w, full wave, 4B/lane
    const float* dsrc = dTg + ((size_t)b * 8 + w) * NN + lane;

    {   // prologue: stage chunk 0 into bufP
        gload_lds16(hsrc, (_Float16*)bufP + (w << 9));
        gload_lds4(dsrc, (float*)(bufP + 8192) + (w << 6));
    }

    float svA = s[((size_t)b * NN + myrow) * 8 + w];
    float svB = s[((size_t)b * NN + myrow + 16) * 8 + w];
    float md = fdec(maxd[b * 8 + w]);
    float MA = fmaxf(svA + md, 0.f);
    float MB = fmaxf(svB + md, 0.f);
    const unsigned long long* abr = adjb + ((size_t)b * NN + myrow) * 8;
    int rq8 = rq * 8;

    f16x8 ones;
#pragma unroll
    for (int e = 0; e < 8; ++e) ones[e] = (_Float16)1.0f;

    f32x4 accA[4], accB[4], accrsA, accrsB;
#pragma unroll
    for (int e = 0; e < 4; ++e) { accrsA[e] = 0.f; accrsB[e] = 0.f; }
#pragma unroll
    for (int ft = 0; ft < 4; ++ft)
#pragma unroll
        for (int e = 0; e < 4; ++e) { accA[ft][e] = 0.f; accB[ft][e] = 0.f; }

    unsigned long long mbA = abr[0], mbB = abr[128];   // row +16 = +128 u64s
    __syncthreads();                           // buf0 staged

    for (int jcx = 0; jcx < 8; ++jcx) {
        int jc = jcx * 64;
        char* cur = (jcx & 1) ? bufQ : bufP;
        char* nxt = (jcx & 1) ? bufP : bufQ;
        if (jcx < 7) {                         // stage NEXT chunk into idle buf
            gload_lds16(hsrc + jc + 64, (_Float16*)nxt + (w << 9));
            gload_lds4(dsrc + jc + 64, (float*)(nxt + 8192) + (w << 6));
        }
        unsigned long long mbnA = (jcx < 7) ? abr[jcx + 1] : 0ull;
        unsigned long long mbnB = (jcx < 7) ? abr[jcx + 129] : 0ull;
        const _Float16* hTc = (const _Float16*)cur;
        const float* ddl = (const float*)(cur + 8192) + (w << 6);
        unsigned int mlA = (unsigned)mbA, mhA = (unsigned)(mbA >> 32);
        unsigned int mlB = (unsigned)mbB, mhB = (unsigned)(mbB >> 32);
#pragma unroll
        for (int ks = 0; ks < 2; ++ks) {
            float dd[8];
            *(float4*)&dd[0] = *(const float4*)(ddl + ks * 32 + rq8);
            *(float4*)&dd[4] = *(const float4*)(ddl + ks * 32 + rq8 + 4);
            unsigned int mbyA = ((ks ? mhA : mlA) >> rq8) & 0xffu;
            unsigned int mbyB = ((ks ? mhB : mlB) >> rq8) & 0xffu;
            AF aA, aB;
            PBUILD(aA, svA, MA, mbyA, dd);
            PBUILD(aB, svB, MB, mbyB, dd);
            accrsA = MFMA16(aA.v, ones, accrsA);
            accrsB = MFMA16(aB.v, ones, accrsB);
#pragma unroll
            for (int ft = 0; ft < 4; ++ft) {   // 1 bh read -> 2 MFMAs
                int f = ft * 16 + cn;
                f16x8 bh = *(const f16x8*)&hTc[f * 64 + (((ks * 4 + rq) ^ (f & 7)) * 8)];
                accA[ft] = MFMA16(aA.v, bh, accA[ft]);
                accB[ft] = MFMA16(aB.v, bh, accB[ft]);
            }
        }
        mbA = mbnA; mbB = mbnB;
        __syncthreads();                       // drains next-chunk staging too
    }

    float invrA[4], invrB[4];
#pragma unroll
    for (int r = 0; r < 4; ++r) {
        invrA[r] = 1.0f / accrsA[r];
        invrB[r] = 1.0f / accrsB[r];
    }

    if (MODE == 0) {
        // ---- x1 tile for head w (norm + ELU), [8][32][64] fp16, XOR-swizzled
        _Float16* x1all = (_Float16*)smem;     // 32KB
#pragma unroll
        for (int rt = 0; rt < 2; ++rt)
#pragma unroll
            for (int ft = 0; ft < 4; ++ft)
#pragma unroll
                for (int r = 0; r < 4; ++r) {
                    int il = rt * 16 + rq * 4 + r;
                    float v = rt ? accB[ft][r] * invrB[r]
                                 : accA[ft][r] * invrA[r];
                    v = v > 0.f ? v : __expf(v) - 1.f;   // ELU
                    int f = ft * 16 + cn;
                    x1all[w * 2048 + il * 64 + (((f >> 3) ^ (il & 7)) * 8) + (f & 7)] =
                        (_Float16)v;
                }
        __syncthreads();
        // ---- gemm1: col-tile (w&3), K-half (w>>2), 2 row-tiles per wave;
        // each W1T fragment read serves 2 MFMAs. B direct from L2 W1T.
        f32x4 g1A, g1B;
#pragma unroll
        for (int e = 0; e < 4; ++e) { g1A[e] = 0.f; g1B[e] = 0.f; }
        int nn = (w & 3) * 16 + cn, kh = w >> 2;
        const _Float16* wb = W1T + (size_t)nn * 512;
#pragma unroll
        for (int kc2 = 0; kc2 < 4; ++kc2) {
            int kc = kh * 4 + kc2;
#pragma unroll
            for (int ks = 0; ks < 2; ++ks) {
                f16x8 bh = *(const f16x8*)(wb + kc * 64 +
                                           (((ks * 4 + rq) ^ (nn & 7)) * 8));
                f16x8 ahA = *(const f16x8*)&x1all[kc * 2048 + cn * 64 +
                                                  (((ks * 4 + rq) ^ (cn & 7)) * 8)];
                f16x8 ahB = *(const f16x8*)&x1all[kc * 2048 + (16 + cn) * 64 +
                                                  (((ks * 4 + rq) ^ (cn & 7)) * 8)];
                g1A = MFMA16(ahA, bh, g1A);
                g1B = MFMA16(ahB, bh, g1B);
            }
        }
        __syncthreads();                       // x1all reads done
        float* ct = (float*)smem;              // [2kh][32][66] = 16.9KB
        float* asd_f = (float*)(smem + 33280); // 4KB
        float* dmax = (float*)(smem + 37376);  // 1KB
#pragma unroll
        for (int r = 0; r < 4; ++r) {
            ct[kh * 2112 + (rq * 4 + r) * 66 + nn] = g1A[r];
            ct[kh * 2112 + (16 + rq * 4 + r) * 66 + nn] = g1B[r];
        }
        if (t < 256)
            ((float4*)asd_f)[t] = (t < 128) ? ((const float4*)a_src)[t]
                                            : ((const float4*)a_dst)[t - 128];
        __syncthreads();
        for (int idx = t; idx < 2112; idx += 512) ct[idx] += ct[2112 + idx];
        __syncthreads();
        epi32(ct, asd_f, row0, t, s_out, dTg_out, hpT_out, dmax, maxd_out);
    } else {
        float* red = (float*)smem;             // [4][32][64] fp32 = 32KB
#pragma unroll
        for (int ph = 0; ph < 2; ++ph) {
            if ((w >> 2) == ph) {
#pragma unroll
                for (int rt = 0; rt < 2; ++rt)
#pragma unroll
                    for (int ft = 0; ft < 4; ++ft)
#pragma unroll
                        for (int r = 0; r < 4; ++r) {
                            int il = rt * 16 + rq * 4 + r;
                            float v = rt ? accB[ft][r] * invrB[r]
                                         : accA[ft][r] * invrA[r];
                            int off = (w & 3) * 2048 + il * 64 + ft * 16 + cn;
                            if (ph == 0) red[off] = v;
                            else         red[off] += v;
                        }
            }
            __syncthreads();
        }
#pragma unroll
        for (int u = 0; u < 4; ++u) {
            int idx = t + u * 512;
            int il = idx >> 6, f = idx & 63;
            float sum = red[il * 64 + f] + red[2048 + il * 64 + f]
                      + red[4096 + il * 64 + f] + red[6144 + il * 64 + f];
            o_f[((size_t)b * NN + i0 + il) * 64 + f] = sum * 0.125f;
        }
    }
}

extern "C" void kernel_launch(void* const* d_in, const int* in_sizes, int n_in,
                              void* d_out, int out_size, void* d_ws, size_t ws_size,
                              hipStream_t stream) {
    const float* x      = (const float*)d_in[0];
    const float* adj    = (const float*)d_in[1];
    const float* W0     = (const float*)d_in[4];
    const float* a_src0 = (const float*)d_in[5];
    const float* a_dst0 = (const float*)d_in[6];
    const float* W1     = (const float*)d_in[7];
    const float* a_src1 = (const float*)d_in[8];
    const float* a_dst1 = (const float*)d_in[9];
    float* out = (float*)d_out;

    float* ws = (float*)d_ws;
    const size_t R = (size_t)BB * NN;            // 16384 rows
    const size_t BHN = (size_t)BB * 8 * NN;      // 131072
    float* s0    = ws;                           // R*8
    float* dTg0  = s0 + R * 8;
    float* s1    = dTg0 + BHN;
    float* dTg1  = s1 + R * 8;
    unsigned* maxd0 = (unsigned*)(dTg1 + BHN);   // 256 keys
    unsigned* maxd1 = maxd0 + 256;               // 256 keys
    _Float16* hp0T = (_Float16*)(maxd1 + 256);   // 32*64*512
    _Float16* hp1T = hp0T + (size_t)BB * 64 * NN;
    _Float16* W0T  = hp1T + (size_t)BB * 64 * NN;   // 64*64
    _Float16* W1T  = W0T + (size_t)64 * 64;         // 64*512
    unsigned long long* adjb = (unsigned long long*)(W1T + (size_t)64 * 512); // 16384*8B

    k_wt_prep<<<18, 256, 0, stream>>>(W0, W0T, W1, W1T, maxd0);
    k_gemm0<<<1024, 256, 0, stream>>>(x, W0T, a_src0, a_dst0, adj, adjb,
                                      s0, dTg0, hp0T, maxd0);
    k_attn_fused<0><<<512, 512, 0, stream>>>(adjb, s0, dTg0, maxd0, hp0T,
                                             W1T, a_src1, a_dst1,
                                             s1, dTg1, hp1T, maxd1, nullptr);
    k_attn_fused<1><<<512, 512, 0, stream>>>(adjb, s1, dTg1, maxd1, hp1T,
                                             nullptr, nullptr, nullptr,
                                             nullptr, nullptr, nullptr, nullptr, out);
}